// Round 12
// baseline (795.454 us; speedup 1.0000x reference)
//
#include <hip/hip_runtime.h>
#include <hip/hip_bf16.h>
#include <float.h>

#define NN 3072
#define MM 3072
#define DD 64
#define KK 8
#define NPROB 24
#define NBLK 480          // persistent k_sink blocks (512 thr each; ~2/CU, balanced)

constexpr float C_EPS   = 0.0025f;   // blur^2
constexpr int   C_NITER = 30;
constexpr float LOG2E = 1.4426950408889634f;
constexpr float LN2F  = 0.6931471805599453f;
constexpr float L2_SCAL2 = -0.6438561897747247f;   // log2(0.64)

__device__ __forceinline__ float ex2(float x){ return __builtin_amdgcn_exp2f(x); }
__device__ __forceinline__ float lg2(float x){ return __builtin_amdgcn_logf(x); }

// system-scope relaxed ops: die-level coherent LLC, NO cache invalidation.
__device__ __forceinline__ void  sst(float* p, float v){
    __hip_atomic_store(p, v, __ATOMIC_RELAXED, __HIP_MEMORY_SCOPE_SYSTEM);
}
__device__ __forceinline__ float sld(const float* p){
    return __hip_atomic_load((float*)p, __ATOMIC_RELAXED, __HIP_MEMORY_SCOPE_SYSTEM);
}

// workspace layout in 4-byte units
#define U_FILL 0        // 8 floats  (zeroed by memset)
#define U_MAXC 8        // 4 uints   (zeroed)
#define U_CNTX 12       // 8 int
#define U_CNTY 20       // 8 int
#define U_POSX 28       // 8 int
#define U_POSY 36       // 8 int  -> memset covers [0,44)
#define U_OFFX 44       // 9 int
#define U_OFFY 53       // 9 int
#define U_PNX  64       // 24 int
#define U_PNY  88
#define U_PRB  112
#define U_PCB  136
#define U_PRS  160
#define U_PCS  184
#define U_PCOFF 208     // 25 int
#define U_PTOF  233     // 24 int  (C^T offsets; == PCOFF for symmetric xx/yy)
#define U_TOFF  257     // 25 int
#define U_ACCF  288     // 24 float (zeroed in k_offsets)
#define U_ACCG  312     // 24 float
#define U_TPPA  336     // 24 int team sizes
#define U_ASGN  384     // NBLK ints: (p<<16)|sb
#define U_BAR   896     // 24 teams x 64 ints: cnt at p*64, gen at p*64+32 (zeroed)
#define U_XSQ  2432     // 3072 float
#define U_YSQ  5504     // 3072 float
#define U_PRED 8576     // 3072 int
#define U_ROWS 11648    // 3072 int
#define U_COLS 14720    // 3072 int
#define U_FPOT 17792    // 24*3072 float potentials f
#define U_GPOT 91520    // 24*3072 float potentials g (zeroed by memset)
#define U_SUBC 165248   // compact submatrices C, then appended C^T blocks (floats)

// ---------------- kernel 1: merged prep (blocks 0-11: x side, 12-23: y side) -------------
__global__ __launch_bounds__(256) void k_prep(const float* __restrict__ x,
                                              const float* __restrict__ y,
                                              const float* __restrict__ cc,
                                              const int* __restrict__ predt,
                                              float* wf, int* wi) {
    int tid = threadIdx.x;
    if (blockIdx.x < 12) {
        __shared__ __align__(16) float c_s[KK][DD];
        __shared__ float csq_s[KK];
        __shared__ float fpart[KK];
        for (int e = tid; e < KK*DD; e += 256) c_s[e>>6][e&63] = cc[e];
        if (tid < KK) fpart[tid] = 0.f;
        __syncthreads();
        if (tid < KK) { float s=0.f; for (int d=0; d<DD; ++d){ float v=c_s[tid][d]; s+=v*v; } csq_s[tid]=s; }
        __syncthreads();
        int i = blockIdx.x*256 + tid;
        if (i < NN) {
            const float4* xr = (const float4*)(x + (size_t)i*DD);
            float4 xv[16];
            float xs = 0.f;
            #pragma unroll
            for (int q=0;q<16;++q){ xv[q]=xr[q];
                xs += xv[q].x*xv[q].x + xv[q].y*xv[q].y + xv[q].z*xv[q].z + xv[q].w*xv[q].w; }
            float dk[KK];
            #pragma unroll
            for (int k=0;k<KK;++k){
                const float4* cr = (const float4*)(&c_s[k][0]);
                float dot=0.f;
                #pragma unroll
                for (int q=0;q<16;++q){ float4 cv=cr[q];
                    dot += xv[q].x*cv.x + xv[q].y*cv.y + xv[q].z*cv.z + xv[q].w*cv.w; }
                dk[k] = xs + csq_s[k] - 2.f*dot;
            }
            float dmin = dk[0]; int am=0;
            #pragma unroll
            for (int k=1;k<KK;++k){ if (dk[k] < dmin){ dmin=dk[k]; am=k; } }
            float se=0.f; float ek[KK];
            #pragma unroll
            for (int k=0;k<KK;++k){ ek[k] = ex2((dmin-dk[k])*LOG2E); se+=ek[k]; }
            float inv = 1.f/se;
            #pragma unroll
            for (int k=0;k<KK;++k) atomicAdd(&fpart[k], ek[k]*inv);
            wf[U_XSQ + i] = xs;
            wi[U_PRED + i] = am;
            atomicAdd(&wi[U_CNTX + am], 1);
        }
        __syncthreads();
        if (tid < KK) atomicAdd(&wf[U_FILL + tid], fpart[tid]);
    } else {
        int j = (blockIdx.x-12)*256 + tid;
        if (j < MM) {
            const float4* yr = (const float4*)(y + (size_t)j*DD);
            float s=0.f;
            #pragma unroll
            for (int q=0;q<16;++q){ float4 v=yr[q]; s += v.x*v.x+v.y*v.y+v.z*v.z+v.w*v.w; }
            wf[U_YSQ + j] = s;
            atomicAdd(&wi[U_CNTY + predt[j]], 1);
        }
    }
}

// ---------------- kernel 3: prefix sums, tables, team allocation, loss_fil ----------------
__global__ void k_offsets(const float* __restrict__ ftarg, float* wf, int* wi, float* out) {
    if (threadIdx.x != 0) return;
    int offx=0, offy=0;
    wi[U_OFFX]=0; wi[U_OFFY]=0;
    for (int k=0;k<KK;++k){
        offx += wi[U_CNTX+k]; wi[U_OFFX+k+1]=offx;
        offy += wi[U_CNTY+k]; wi[U_OFFY+k+1]=offy;
    }
    int co=0, to=0;
    for (int k=0;k<KK;++k){
        int cx=wi[U_CNTX+k], cy=wi[U_CNTY+k];
        bool val = (cx>0)&&(cy>0);
        for (int t=0;t<3;++t){
            int p=k*3+t;
            int nx = val ? (t==2?cy:cx) : 0;
            int ny = val ? (t==1?cx:cy) : 0;
            wi[U_PNX+p]=nx; wi[U_PNY+p]=ny;
            wi[U_PRB+p] = (t==2)? wi[U_OFFY+k] : wi[U_OFFX+k];
            wi[U_PCB+p] = (t==1)? wi[U_OFFX+k] : wi[U_OFFY+k];
            wi[U_PRS+p] = (t==2)?1:0;
            wi[U_PCS+p] = (t==1)?0:1;
            wi[U_PCOFF+p]=co; co += nx*ny;
            wi[U_TOFF+p]=to; to += ((nx+31)>>5)*((ny+31)>>5);
            wf[U_ACCF+p]=0.f; wf[U_ACCG+p]=0.f;
        }
    }
    wi[U_PCOFF+NPROB]=co; wi[U_TOFF+NPROB]=to;
    // C^T blocks appended after all C; xx/yy are symmetric so CT == C
    int cto = co;
    for (int p=0;p<NPROB;++p){
        if (p%3 == 0){ wi[U_PTOF+p] = cto; cto += wi[U_PNX+p]*wi[U_PNY+p]; }
        else         { wi[U_PTOF+p] = wi[U_PCOFF+p]; }
    }
    // ---- work-proportional team allocation over NBLK blocks ----
    long long wsum = 0;
    int wk[NPROB], quota[NPROB], done[NPROB];
    for (int p=0;p<NPROB;++p){
        int nx=wi[U_PNX+p], ny=wi[U_PNY+p];
        wk[p] = (nx>0 && ny>0) ? nx*ny : 0;
        wsum += wk[p];
    }
    if (wsum == 0){
        for (int b=0;b<NBLK;++b) wi[U_ASGN+b] = (0xFF<<16);
        for (int p=0;p<NPROB;++p) wi[U_TPPA+p] = 0;
    } else {
        int tot=0;
        for (int p=0;p<NPROB;++p){
            quota[p] = (wk[p]>0) ? (int)(((long long)NBLK*wk[p])/wsum) : 0;
            if (wk[p]>0 && quota[p]<1) quota[p]=1;
            tot += quota[p];
        }
        while (tot < NBLK){
            int best=-1; float br=-1.f;
            for (int p=0;p<NPROB;++p) if (wk[p]>0){
                float r = (float)wk[p]/(float)quota[p];
                if (r>br){br=r;best=p;}
            }
            quota[best]++; tot++;
        }
        while (tot > NBLK){
            int best=-1; float br=3.4e38f;
            for (int p=0;p<NPROB;++p) if (quota[p]>1){
                float r = (float)wk[p]/(float)(quota[p]-1);
                if (r<br){br=r;best=p;}
            }
            if (best<0) break;
            quota[best]--; tot--;
        }
        for (int p=0;p<NPROB;++p){ done[p]=0; wi[U_TPPA+p]=quota[p]; }
        int asg=0;
        while (asg < NBLK){
            for (int p=0;p<NPROB && asg<NBLK;++p)
                if (done[p] < quota[p]){ wi[U_ASGN+asg] = (p<<16)|done[p]; done[p]++; asg++; }
        }
    }
    float lf=0.f;
    for (int k=0;k<KK;++k){ float fx = wf[U_FILL+k]/(float)NN; float dd = fx - ftarg[k]; lf += dd*dd; }
    out[0] = lf/(float)KK;
}

// ---------------- kernel 4: scatter compact index lists ----------------
__global__ __launch_bounds__(256) void k_scatter(const int* __restrict__ predt, int* wi) {
    int b = blockIdx.x;
    if (b < 12) {
        int i = b*256 + threadIdx.x;
        if (i < NN){ int k = wi[U_PRED+i]; int p = atomicAdd(&wi[U_POSX+k],1);
                     wi[U_ROWS + wi[U_OFFX+k] + p] = i; }
    } else {
        int j = (b-12)*256 + threadIdx.x;
        if (j < MM){ int k = predt[j]; int p = atomicAdd(&wi[U_POSY+k],1);
                     wi[U_COLS + wi[U_OFFY+k] + p] = j; }
    }
}

// ---------------- kernel 5: exact max, 128x128 tiles, 8x8/thread strided, tri-skip -------
__global__ __launch_bounds__(256) void k_maxmat(const float* __restrict__ x,
                                                const float* __restrict__ y,
                                                float* wf, int* wi) {
    int z = blockIdx.z;
    if (z && blockIdx.y > blockIdx.x) return;   // xx/yy symmetric: upper triangle suffices
    const float* A = (z==2)? y : x;
    const float* B = (z==0)? y : ((z==1)? x : y);
    int aqo = (z==2)? U_YSQ : U_XSQ;
    int bqo = (z==1)? U_XSQ : U_YSQ;
    __shared__ float la[128][65];
    __shared__ float lb[128][65];
    __shared__ float laq[128], lbq[128];
    __shared__ float wred[4];
    int tid = threadIdx.x;
    int i0 = blockIdx.y*128, j0 = blockIdx.x*128;
    #pragma unroll
    for (int q=0;q<8;++q){
        int idx = tid + q*256;            // 0..2047 : 128 rows x 16 float4
        int r = idx>>4, c4 = (idx&15)<<2;
        float4 va = *(const float4*)(A + (size_t)(i0+r)*DD + c4);
        la[r][c4]=va.x; la[r][c4+1]=va.y; la[r][c4+2]=va.z; la[r][c4+3]=va.w;
        float4 vb = *(const float4*)(B + (size_t)(j0+r)*DD + c4);
        lb[r][c4]=vb.x; lb[r][c4+1]=vb.y; lb[r][c4+2]=vb.z; lb[r][c4+3]=vb.w;
    }
    if (tid < 128) laq[tid] = wf[aqo + i0 + tid];
    else           lbq[tid-128] = wf[bqo + j0 + (tid-128)];
    __syncthreads();
    int tx = tid & 15, ty = tid >> 4;
    float acc[8][8];
    #pragma unroll
    for (int u=0;u<8;++u)
        #pragma unroll
        for (int s=0;s<8;++s) acc[u][s]=0.f;
    for (int d=0; d<DD; ++d){
        float av[8], bv[8];
        #pragma unroll
        for (int u=0;u<8;++u) av[u]=la[ty+16*u][d];
        #pragma unroll
        for (int s=0;s<8;++s) bv[s]=lb[tx+16*s][d];
        #pragma unroll
        for (int u=0;u<8;++u)
            #pragma unroll
            for (int s=0;s<8;++s) acc[u][s] = fmaf(av[u], bv[s], acc[u][s]);
    }
    float m = 0.f;
    #pragma unroll
    for (int u=0;u<8;++u){
        float aq = laq[ty+16*u];
        #pragma unroll
        for (int s=0;s<8;++s){
            float cst = 0.5f*(aq + lbq[tx+16*s]) - acc[u][s];
            m = fmaxf(m, cst);
        }
    }
    #pragma unroll
    for (int o=32;o;o>>=1) m = fmaxf(m, __shfl_xor(m,o));
    int wid = tid>>6;
    if ((tid&63)==0) wred[wid]=m;
    __syncthreads();
    if (tid==0){
        float mm = fmaxf(fmaxf(wred[0],wred[1]),fmaxf(wred[2],wred[3]));
        atomicMax((unsigned int*)&wi[U_MAXC+z], __float_as_uint(mm));
    }
}

// ---------------- kernel 6: gather compact cost submatrices (+ C^T for xy) ----------------
__global__ __launch_bounds__(256) void k_gather(const float* __restrict__ x,
                                                const float* __restrict__ y,
                                                float* wf, int* wi) {
    __shared__ float xs_[32][65], ys_[32][65];
    __shared__ float cs_[32][33];
    __shared__ float rq[32], cq[32];
    __shared__ int toff_s[NPROB+1];
    int tid = threadIdx.x;
    if (tid <= NPROB) toff_s[tid] = wi[U_TOFF+tid];
    __syncthreads();
    int total = toff_s[NPROB];
    for (int tix = blockIdx.x; tix < total; tix += gridDim.x){
        int p = 0;
        while (toff_s[p+1] <= tix) ++p;
        int nx = wi[U_PNX+p], ny = wi[U_PNY+p];
        int tpr = (ny+31)>>5;
        int loc = tix - toff_s[p];
        int i0 = (loc/tpr)<<5, j0 = (loc%tpr)<<5;
        int rbase = wi[U_PRB+p], cbase = wi[U_PCB+p];
        int rs = wi[U_PRS+p], cs = wi[U_PCS+p];
        const float* rsrc = rs? y : x;
        const float* csrc = cs? y : x;
        const int* rlist = wi + (rs? U_COLS : U_ROWS);
        const int* clist = wi + (cs? U_COLS : U_ROWS);
        int rqo = rs? U_YSQ : U_XSQ;
        int cqo = cs? U_YSQ : U_XSQ;
        size_t coff = (size_t)wi[U_PCOFF+p];
        #pragma unroll
        for (int q=0;q<2;++q){
            int idx4 = tid + q*256;      // 0..511
            int r = idx4>>4, c = (idx4&15)<<2;
            if (i0 + r < nx){
                int gi = rlist[rbase + i0 + r];
                float4 v = *(const float4*)(rsrc + (size_t)gi*DD + c);
                xs_[r][c]=v.x; xs_[r][c+1]=v.y; xs_[r][c+2]=v.z; xs_[r][c+3]=v.w;
                if (c==0) rq[r] = wf[rqo + gi];
            }
            if (j0 + r < ny){
                int gj = clist[cbase + j0 + r];
                float4 v = *(const float4*)(csrc + (size_t)gj*DD + c);
                ys_[r][c]=v.x; ys_[r][c+1]=v.y; ys_[r][c+2]=v.z; ys_[r][c+3]=v.w;
                if (c==0) cq[r] = wf[cqo + gj];
            }
        }
        __syncthreads();
        int r = tid>>3, cb = (tid&7)<<2;
        float cv[4] = {0.f,0.f,0.f,0.f};
        if (i0 + r < nx){
            float acc[4] = {0.f,0.f,0.f,0.f};
            for (int d=0; d<DD; ++d){
                float xv = xs_[r][d];
                #pragma unroll
                for (int q=0;q<4;++q) acc[q] += xv*ys_[cb+q][d];
            }
            float* dst = wf + U_SUBC + coff + (size_t)(i0+r)*ny + j0;
            #pragma unroll
            for (int q=0;q<4;++q){
                int j = cb+q;
                cv[q] = 0.5f*(rq[r]+cq[j]) - acc[q];
                if (j0 + j < ny) dst[j] = cv[q];
            }
        }
        if (p%3 == 0){
            #pragma unroll
            for (int q=0;q<4;++q) cs_[r][cb+q] = cv[q];
            __syncthreads();
            if (j0 + r < ny){
                float* dT = wf + U_SUBC + (size_t)wi[U_PTOF+p] + (size_t)(j0+r)*nx + i0;
                #pragma unroll
                for (int q=0;q<4;++q){
                    int ii = cb+q;
                    if (i0 + ii < nx) dT[ii] = cs_[ii][r];
                }
            }
        }
        __syncthreads();
    }
}

// ---------------- sinkhorn sweep: exact online LSE; 4 rows in flight per wave -----------
#define LD4R(R, JB, D0,D1,D2,D3) { int ja=(JB)+lane; \
    D0=R[ja]; D1=R[ja+64]; D2=R[ja+128]; D3=R[ja+192]; }

#define LD4RC(R, JB, D0,D1,D2,D3) { int ja=(JB)+lane; \
    D0 = (ja      <ncols)? R[ja]     : 0.f; \
    D1 = (ja+64   <ncols)? R[ja+64]  : 0.f; \
    D2 = (ja+128  <ncols)? R[ja+128] : 0.f; \
    D3 = (ja+192  <ncols)? R[ja+192] : 0.f; }

#define PROCF(D0,D1,D2,D3, G0,G1,G2,G3, M, S) { \
    float t0=fmaf(D0,nie2,G0), t1=fmaf(D1,nie2,G1), t2=fmaf(D2,nie2,G2), t3=fmaf(D3,nie2,G3); \
    float cm = fmaxf(fmaxf(t0,t1),fmaxf(t2,t3)); \
    float mn = fmaxf(M, cm); \
    float sm = ex2(t0-mn) + ex2(t1-mn) + ex2(t2-mn) + ex2(t3-mn); \
    S = fmaf(S, ex2(M-mn), sm); \
    M = mn; }

#define PROCR(JB, D0,D1,D2,D3, G0,G1,G2,G3, M, S) { \
    int ja=(JB)+lane; \
    float t0 = (ja     <ncols)? fmaf(D0, nie2, G0) : -3e38f; \
    float t1 = (ja+64  <ncols)? fmaf(D1, nie2, G1) : -3e38f; \
    float t2 = (ja+128 <ncols)? fmaf(D2, nie2, G2) : -3e38f; \
    float t3 = (ja+192 <ncols)? fmaf(D3, nie2, G3) : -3e38f; \
    float cm = fmaxf(fmaxf(t0,t1),fmaxf(t2,t3)); \
    float mn = fmaxf(M, cm); \
    float sm = ex2(t0-mn) + ex2(t1-mn) + ex2(t2-mn) + ex2(t3-mn); \
    S = fmaf(S, ex2(M-mn), sm); \
    M = mn; }

#define MERGE(M, S) { \
    _Pragma("unroll") \
    for (int o=32;o;o>>=1){ \
        float mo=__shfl_xor(M,o), So=__shfl_xor(S,o); \
        float mn=fmaxf(M,mo); S=fmaf(S,ex2(M-mn),So*ex2(mo-mn)); M=mn; } }

// rows [rbeg, rend) of Cb (absolute indexing); per-row math identical to r11 (passed).
template<bool FIN>
__device__ __forceinline__ void sweep(const float* __restrict__ Cb, int ldc, int rbeg, int rend,
                                      int ncols, const float* __restrict__ gs,
                                      float* __restrict__ pot, float ie2, float neL, float l2n,
                                      int lane, float* saccSlot)
{
    float nie2 = -ie2;
    float acc = 0.f;
    int nfull = ncols >> 8;
    int rem   = ncols & 255;
    for (int i0 = rbeg; i0 < rend; i0 += 4){
        int ia = i0;
        bool v1 = (i0+1 < rend), v2 = (i0+2 < rend), v3 = (i0+3 < rend);
        int ib = v1? i0+1 : ia, ic = v2? i0+2 : ia, id2 = v3? i0+3 : ia;
        const float* R0 = Cb + (size_t)ia*ldc;
        const float* R1 = Cb + (size_t)ib*ldc;
        const float* R2 = Cb + (size_t)ic*ldc;
        const float* R3 = Cb + (size_t)id2*ldc;
        float m0=-3e38f,m1=-3e38f,m2=-3e38f,m3=-3e38f;
        float S0=0.f,S1=0.f,S2=0.f,S3=0.f;
        if (nfull){
            float a00,a01,a02,a03, a10,a11,a12,a13, a20,a21,a22,a23, a30,a31,a32,a33;
            float ga0,ga1,ga2,ga3;
            LD4R(R0,0,a00,a01,a02,a03) LD4R(R1,0,a10,a11,a12,a13)
            LD4R(R2,0,a20,a21,a22,a23) LD4R(R3,0,a30,a31,a32,a33)
            { int ja=lane; ga0=gs[ja]; ga1=gs[ja+64]; ga2=gs[ja+128]; ga3=gs[ja+192]; }
            for (int v=1; v<nfull; ++v){
                int jn = v<<8;
                float b00,b01,b02,b03, b10,b11,b12,b13, b20,b21,b22,b23, b30,b31,b32,b33;
                float gb0,gb1,gb2,gb3;
                LD4R(R0,jn,b00,b01,b02,b03) LD4R(R1,jn,b10,b11,b12,b13)
                LD4R(R2,jn,b20,b21,b22,b23) LD4R(R3,jn,b30,b31,b32,b33)
                { int ja=jn+lane; gb0=gs[ja]; gb1=gs[ja+64]; gb2=gs[ja+128]; gb3=gs[ja+192]; }
                PROCF(a00,a01,a02,a03, ga0,ga1,ga2,ga3, m0, S0)
                PROCF(a10,a11,a12,a13, ga0,ga1,ga2,ga3, m1, S1)
                PROCF(a20,a21,a22,a23, ga0,ga1,ga2,ga3, m2, S2)
                PROCF(a30,a31,a32,a33, ga0,ga1,ga2,ga3, m3, S3)
                a00=b00;a01=b01;a02=b02;a03=b03; a10=b10;a11=b11;a12=b12;a13=b13;
                a20=b20;a21=b21;a22=b22;a23=b23; a30=b30;a31=b31;a32=b32;a33=b33;
                ga0=gb0;ga1=gb1;ga2=gb2;ga3=gb3;
            }
            PROCF(a00,a01,a02,a03, ga0,ga1,ga2,ga3, m0, S0)
            PROCF(a10,a11,a12,a13, ga0,ga1,ga2,ga3, m1, S1)
            PROCF(a20,a21,a22,a23, ga0,ga1,ga2,ga3, m2, S2)
            PROCF(a30,a31,a32,a33, ga0,ga1,ga2,ga3, m3, S3)
        }
        if (rem){
            int jb = nfull<<8;
            float c00,c01,c02,c03, c10,c11,c12,c13, c20,c21,c22,c23, c30,c31,c32,c33;
            float gc0,gc1,gc2,gc3;
            LD4RC(R0,jb,c00,c01,c02,c03) LD4RC(R1,jb,c10,c11,c12,c13)
            LD4RC(R2,jb,c20,c21,c22,c23) LD4RC(R3,jb,c30,c31,c32,c33)
            { int ja=jb+lane;
              gc0 = (ja    <ncols)? gs[ja]     : 0.f;
              gc1 = (ja+64 <ncols)? gs[ja+64]  : 0.f;
              gc2 = (ja+128<ncols)? gs[ja+128] : 0.f;
              gc3 = (ja+192<ncols)? gs[ja+192] : 0.f; }
            PROCR(jb, c00,c01,c02,c03, gc0,gc1,gc2,gc3, m0, S0)
            PROCR(jb, c10,c11,c12,c13, gc0,gc1,gc2,gc3, m1, S1)
            PROCR(jb, c20,c21,c22,c23, gc0,gc1,gc2,gc3, m2, S2)
            PROCR(jb, c30,c31,c32,c33, gc0,gc1,gc2,gc3, m3, S3)
        }
        MERGE(m0,S0) MERGE(m1,S1) MERGE(m2,S2) MERGE(m3,S3)
        if (lane==0){
            float v0  = neL*(m0 + lg2(S0) - l2n);
            float w1  = neL*(m1 + lg2(S1) - l2n);
            float w2  = neL*(m2 + lg2(S2) - l2n);
            float w3  = neL*(m3 + lg2(S3) - l2n);
            if (FIN){
                acc += v0;
                if (v1) acc += w1;
                if (v2) acc += w2;
                if (v3) acc += w3;
            } else {
                sst(&pot[ia], v0);
                if (v1) sst(&pot[ib], w1);
                if (v2) sst(&pot[ic], w2);
                if (v3) sst(&pot[id2], w3);
            }
        }
    }
    if (FIN && lane==0 && acc != 0.f) atomicAdd(saccSlot, acc);
}

// ---------------- per-team barrier: RELAXED atomics only (no cache invalidation) --------
__device__ __forceinline__ void tbar(int* cnt, int* gen, int tpp){
    __syncthreads();
    if (threadIdx.x == 0){
        asm volatile("s_waitcnt vmcnt(0)" ::: "memory");
        int g0 = __hip_atomic_load(gen, __ATOMIC_RELAXED, __HIP_MEMORY_SCOPE_AGENT);
        int a  = __hip_atomic_fetch_add(cnt, 1, __ATOMIC_RELAXED, __HIP_MEMORY_SCOPE_AGENT);
        if (a == tpp-1){
            __hip_atomic_store(cnt, 0, __ATOMIC_RELAXED, __HIP_MEMORY_SCOPE_AGENT);
            __hip_atomic_fetch_add(gen, 1, __ATOMIC_RELAXED, __HIP_MEMORY_SCOPE_AGENT);
        } else {
            int spins = 0;
            while (__hip_atomic_load(gen, __ATOMIC_RELAXED, __HIP_MEMORY_SCOPE_AGENT) == g0){
                __builtin_amdgcn_s_sleep(2);
                if (++spins > 200000) break;   // failsafe: finite wrong run, never a hang
            }
        }
    }
    __syncthreads();
}

// ---------------- kernel 7: persistent sinkhorn — per-wave balanced row ranges ----------
__global__ __launch_bounds__(512) void k_sink(float* wf, int* wi, float* out) {
    int av = wi[U_ASGN + blockIdx.x];
    int p  = av>>16, sb = av & 0xFFFF;
    if (p >= NPROB) return;
    int nx = wi[U_PNX+p], ny = wi[U_PNY+p];
    if (nx <= 0 || ny <= 0) return;
    int tpp = wi[U_TPPA+p];
    int tid = threadIdx.x, w = tid>>6, lane = tid&63;
    int W  = tpp*8;                   // waves in team
    int gw = sb*8 + w;                // this wave's global index in team
    float eps0 = fmaxf(__uint_as_float((unsigned)wi[U_MAXC + (p%3)]), C_EPS);
    const float* C  = wf + U_SUBC + (size_t)wi[U_PCOFF+p];
    const float* CT = wf + U_SUBC + (size_t)wi[U_PTOF+p];
    float* f = wf + U_FPOT + p*3072;
    float* g = wf + U_GPOT + p*3072;
    float l2ny = lg2((float)ny), l2nx = lg2((float)nx);
    int* cnt = wi + U_BAR + p*64;
    int* gen = cnt + 32;
    int frb = (int)(((long long)gw*nx)/W),   fre = (int)(((long long)(gw+1)*nx)/W);
    int grb = (int)(((long long)gw*ny)/W),   gre = (int)(((long long)(gw+1)*ny)/W);
    __shared__ float gs[3072];

    for (int it=0; it<C_NITER; ++it){
        float eps = fmaxf(eps0*ex2((float)it*L2_SCAL2), C_EPS);
        float ie2 = LOG2E/eps, neL = -eps*LN2F;
        for (int j=tid; j<ny; j+=512) gs[j] = sld(g+j)*ie2;
        __syncthreads();
        sweep<false>(C, ny, frb, fre, ny, gs, f, ie2, neL, l2ny, lane, nullptr);
        tbar(cnt, gen, tpp);
        for (int i=tid; i<nx; i+=512) gs[i] = sld(f+i)*ie2;
        __syncthreads();
        sweep<false>(CT, nx, grb, gre, nx, gs, g, ie2, neL, l2nx, lane, nullptr);
        tbar(cnt, gen, tpp);
    }
    {
        float ie2 = LOG2E/C_EPS, neL = -C_EPS*LN2F;
        for (int j=tid; j<ny; j+=512) gs[j] = sld(g+j)*ie2;
        __syncthreads();
        sweep<true>(C, ny, frb, fre, ny, gs, nullptr, ie2, neL, l2ny, lane, &wf[U_ACCF+p]);
        __syncthreads();
        for (int i=tid; i<nx; i+=512) gs[i] = sld(f+i)*ie2;
        __syncthreads();
        sweep<true>(CT, nx, grb, gre, nx, gs, nullptr, ie2, neL, l2nx, lane, &wf[U_ACCG+p]);
    }
}

// ---------------- kernel 8: finalize ----------------
__global__ void k_final(float* wf, int* wi, float* out) {
    if (threadIdx.x != 0 || blockIdx.x != 0) return;
    float s = 0.f;
    for (int p=0; p<NPROB; ++p){
        int nx = wi[U_PNX+p], ny = wi[U_PNY+p];
        if (nx<=0 || ny<=0) continue;
        float wgt = (p%3==0) ? 1.f : -0.5f;
        s += wgt * (wf[U_ACCF+p]/(float)nx + wf[U_ACCG+p]/(float)ny);
    }
    out[0] += s;
}

extern "C" void kernel_launch(void* const* d_in, const int* in_sizes, int n_in,
                              void* d_out, int out_size, void* d_ws, size_t ws_size,
                              hipStream_t stream) {
    const float* x     = (const float*)d_in[0];
    const float* y     = (const float*)d_in[1];
    const float* cc    = (const float*)d_in[2];
    const float* ft    = (const float*)d_in[3];
    const int*   predt = (const int*)d_in[4];
    float* out = (float*)d_out;
    float* wf = (float*)d_ws;
    int*   wi = (int*)d_ws;

    hipMemsetAsync(d_ws, 0, 44*sizeof(int), stream);                      // counters/maxes/fillings
    hipMemsetAsync(wi + U_BAR, 0, 24*64*sizeof(int), stream);             // team barriers
    hipMemsetAsync(wf + U_GPOT, 0, NPROB*3072*sizeof(float), stream);     // g potentials start at 0

    k_prep<<<24, 256, 0, stream>>>(x, y, cc, predt, wf, wi);
    k_offsets<<<1, 64, 0, stream>>>(ft, wf, wi, out);   // out[0]=loss_fil; tables; team alloc
    k_scatter<<<24, 256, 0, stream>>>(predt, wi);
    k_maxmat<<<dim3(24,24,3), 256, 0, stream>>>(x, y, wf, wi);
    k_gather<<<1024, 256, 0, stream>>>(x, y, wf, wi);

    k_sink<<<NBLK, 512, 0, stream>>>(wf, wi, out);      // persistent, fence-free teams
    k_final<<<1, 64, 0, stream>>>(wf, wi, out);
}

// Round 14
// 695.215 us; speedup vs baseline: 1.1442x; 1.1442x over previous
//
#include <hip/hip_runtime.h>
#include <hip/hip_bf16.h>
#include <float.h>

#define NN 3072
#define MM 3072
#define DD 64
#define KK 8
#define NPROB 24
#define NBLK 480          // persistent k_sink blocks (512 thr each; ~2/CU, balanced)

constexpr float C_EPS   = 0.0025f;   // blur^2
constexpr int   C_NITER = 30;
constexpr float LOG2E = 1.4426950408889634f;
constexpr float LN2F  = 0.6931471805599453f;
constexpr float L2_SCAL2 = -0.6438561897747247f;   // log2(0.64)

__device__ __forceinline__ float ex2(float x){ return __builtin_amdgcn_exp2f(x); }
__device__ __forceinline__ float lg2(float x){ return __builtin_amdgcn_logf(x); }

// system-scope relaxed ops: die-level coherent LLC, NO cache invalidation.
__device__ __forceinline__ void  sst(float* p, float v){
    __hip_atomic_store(p, v, __ATOMIC_RELAXED, __HIP_MEMORY_SCOPE_SYSTEM);
}
__device__ __forceinline__ float sld(const float* p){
    return __hip_atomic_load((float*)p, __ATOMIC_RELAXED, __HIP_MEMORY_SCOPE_SYSTEM);
}

// workspace layout in 4-byte units
#define U_FILL 0        // 8 floats  (zeroed by memset)
#define U_MAXC 8        // 4 uints   (zeroed)
#define U_CNTX 12       // 8 int
#define U_CNTY 20       // 8 int
#define U_POSX 28       // 8 int
#define U_POSY 36       // 8 int
#define U_OFFX 44       // 9 int
#define U_OFFY 53       // 9 int
#define U_PNX  64       // 24 int
#define U_PNY  88
#define U_PRB  112
#define U_PCB  136
#define U_PRS  160
#define U_PCS  184
#define U_PCOFF 208     // 25 int
#define U_PTOF  233     // 24 int  (C^T offsets; == PCOFF for symmetric xx/yy)
#define U_TOFF  257     // 25 int
#define U_ACCF  288     // 24 float (zeroed in k_offsets)
#define U_ACCG  312     // 24 float
#define U_TPPA  336     // 24 int team sizes
#define U_ASGN  384     // NBLK ints: (p<<16)|sb
#define U_BAR   896     // 24 teams x 64 ints: cnt at p*64, gen at p*64+32 (zeroed)
#define U_XSQ  2432     // 3072 float     <- single memset covers [0, 2432)
#define U_YSQ  5504     // 3072 float
#define U_PRED 8576     // 3072 int
#define U_ROWS 11648    // 3072 int
#define U_COLS 14720    // 3072 int
#define U_FPOT 17792    // 24*3072 float potentials f
#define U_GPOT 91520    // 24*3072 float potentials g (zeroed by memset)
#define U_SUBC 165248   // compact submatrices C, then appended C^T blocks (floats)

// ---------------- kernel 1: merged prep (blocks 0-11: x side, 12-23: y side) -------------
__global__ __launch_bounds__(256) void k_prep(const float* __restrict__ x,
                                              const float* __restrict__ y,
                                              const float* __restrict__ cc,
                                              const int* __restrict__ predt,
                                              float* wf, int* wi) {
    int tid = threadIdx.x;
    if (blockIdx.x < 12) {
        __shared__ __align__(16) float c_s[KK][DD];
        __shared__ float csq_s[KK];
        __shared__ float fpart[KK];
        for (int e = tid; e < KK*DD; e += 256) c_s[e>>6][e&63] = cc[e];
        if (tid < KK) fpart[tid] = 0.f;
        __syncthreads();
        if (tid < KK) { float s=0.f; for (int d=0; d<DD; ++d){ float v=c_s[tid][d]; s+=v*v; } csq_s[tid]=s; }
        __syncthreads();
        int i = blockIdx.x*256 + tid;
        if (i < NN) {
            const float4* xr = (const float4*)(x + (size_t)i*DD);
            float4 xv[16];
            float xs = 0.f;
            #pragma unroll
            for (int q=0;q<16;++q){ xv[q]=xr[q];
                xs += xv[q].x*xv[q].x + xv[q].y*xv[q].y + xv[q].z*xv[q].z + xv[q].w*xv[q].w; }
            float dk[KK];
            #pragma unroll
            for (int k=0;k<KK;++k){
                const float4* cr = (const float4*)(&c_s[k][0]);
                float dot=0.f;
                #pragma unroll
                for (int q=0;q<16;++q){ float4 cv=cr[q];
                    dot += xv[q].x*cv.x + xv[q].y*cv.y + xv[q].z*cv.z + xv[q].w*cv.w; }
                dk[k] = xs + csq_s[k] - 2.f*dot;
            }
            float dmin = dk[0]; int am=0;
            #pragma unroll
            for (int k=1;k<KK;++k){ if (dk[k] < dmin){ dmin=dk[k]; am=k; } }
            float se=0.f; float ek[KK];
            #pragma unroll
            for (int k=0;k<KK;++k){ ek[k] = ex2((dmin-dk[k])*LOG2E); se+=ek[k]; }
            float inv = 1.f/se;
            #pragma unroll
            for (int k=0;k<KK;++k) atomicAdd(&fpart[k], ek[k]*inv);
            wf[U_XSQ + i] = xs;
            wi[U_PRED + i] = am;
            atomicAdd(&wi[U_CNTX + am], 1);
        }
        __syncthreads();
        if (tid < KK) atomicAdd(&wf[U_FILL + tid], fpart[tid]);
    } else {
        int j = (blockIdx.x-12)*256 + tid;
        if (j < MM) {
            const float4* yr = (const float4*)(y + (size_t)j*DD);
            float s=0.f;
            #pragma unroll
            for (int q=0;q<16;++q){ float4 v=yr[q]; s += v.x*v.x+v.y*v.y+v.z*v.z+v.w*v.w; }
            wf[U_YSQ + j] = s;
            atomicAdd(&wi[U_CNTY + predt[j]], 1);
        }
    }
}

// ---------------- kernel 3: prefix sums, tables, team allocation, loss_fil ----------------
__global__ void k_offsets(const float* __restrict__ ftarg, float* wf, int* wi, float* out) {
    if (threadIdx.x != 0) return;
    int offx=0, offy=0;
    wi[U_OFFX]=0; wi[U_OFFY]=0;
    for (int k=0;k<KK;++k){
        offx += wi[U_CNTX+k]; wi[U_OFFX+k+1]=offx;
        offy += wi[U_CNTY+k]; wi[U_OFFY+k+1]=offy;
    }
    int co=0, to=0;
    for (int k=0;k<KK;++k){
        int cx=wi[U_CNTX+k], cy=wi[U_CNTY+k];
        bool val = (cx>0)&&(cy>0);
        for (int t=0;t<3;++t){
            int p=k*3+t;
            int nx = val ? (t==2?cy:cx) : 0;
            int ny = val ? (t==1?cx:cy) : 0;
            wi[U_PNX+p]=nx; wi[U_PNY+p]=ny;
            wi[U_PRB+p] = (t==2)? wi[U_OFFY+k] : wi[U_OFFX+k];
            wi[U_PCB+p] = (t==1)? wi[U_OFFX+k] : wi[U_OFFY+k];
            wi[U_PRS+p] = (t==2)?1:0;
            wi[U_PCS+p] = (t==1)?0:1;
            wi[U_PCOFF+p]=co; co += nx*ny;
            wi[U_TOFF+p]=to; to += ((nx+31)>>5)*((ny+31)>>5);
            wf[U_ACCF+p]=0.f; wf[U_ACCG+p]=0.f;
        }
    }
    wi[U_PCOFF+NPROB]=co; wi[U_TOFF+NPROB]=to;
    // C^T blocks appended after all C; xx/yy are symmetric so CT == C
    int cto = co;
    for (int p=0;p<NPROB;++p){
        if (p%3 == 0){ wi[U_PTOF+p] = cto; cto += wi[U_PNX+p]*wi[U_PNY+p]; }
        else         { wi[U_PTOF+p] = wi[U_PCOFF+p]; }
    }
    // ---- work-proportional team allocation over NBLK blocks ----
    long long wsum = 0;
    int wk[NPROB], quota[NPROB], done[NPROB];
    for (int p=0;p<NPROB;++p){
        int nx=wi[U_PNX+p], ny=wi[U_PNY+p];
        wk[p] = (nx>0 && ny>0) ? nx*ny : 0;
        wsum += wk[p];
    }
    if (wsum == 0){
        for (int b=0;b<NBLK;++b) wi[U_ASGN+b] = (0xFF<<16);
        for (int p=0;p<NPROB;++p) wi[U_TPPA+p] = 0;
    } else {
        int tot=0;
        for (int p=0;p<NPROB;++p){
            quota[p] = (wk[p]>0) ? (int)(((long long)NBLK*wk[p])/wsum) : 0;
            if (wk[p]>0 && quota[p]<1) quota[p]=1;
            tot += quota[p];
        }
        while (tot < NBLK){
            int best=-1; float br=-1.f;
            for (int p=0;p<NPROB;++p) if (wk[p]>0){
                float r = (float)wk[p]/(float)quota[p];
                if (r>br){br=r;best=p;}
            }
            quota[best]++; tot++;
        }
        while (tot > NBLK){
            int best=-1; float br=3.4e38f;
            for (int p=0;p<NPROB;++p) if (quota[p]>1){
                float r = (float)wk[p]/(float)(quota[p]-1);
                if (r<br){br=r;best=p;}
            }
            if (best<0) break;
            quota[best]--; tot--;
        }
        for (int p=0;p<NPROB;++p){ done[p]=0; wi[U_TPPA+p]=quota[p]; }
        int asg=0;
        while (asg < NBLK){
            for (int p=0;p<NPROB && asg<NBLK;++p)
                if (done[p] < quota[p]){ wi[U_ASGN+asg] = (p<<16)|done[p]; done[p]++; asg++; }
        }
    }
    float lf=0.f;
    for (int k=0;k<KK;++k){ float fx = wf[U_FILL+k]/(float)NN; float dd = fx - ftarg[k]; lf += dd*dd; }
    out[0] = lf/(float)KK;
}

// ---------------- kernel 4: scatter compact index lists ----------------
__global__ __launch_bounds__(256) void k_scatter(const int* __restrict__ predt, int* wi) {
    int b = blockIdx.x;
    if (b < 12) {
        int i = b*256 + threadIdx.x;
        if (i < NN){ int k = wi[U_PRED+i]; int p = atomicAdd(&wi[U_POSX+k],1);
                     wi[U_ROWS + wi[U_OFFX+k] + p] = i; }
    } else {
        int j = (b-12)*256 + threadIdx.x;
        if (j < MM){ int k = predt[j]; int p = atomicAdd(&wi[U_POSY+k],1);
                     wi[U_COLS + wi[U_OFFY+k] + p] = j; }
    }
}

// ---------------- kernel 5: exact max, 128x128 tiles, 8x8/thread strided, tri-skip -------
__global__ __launch_bounds__(256) void k_maxmat(const float* __restrict__ x,
                                                const float* __restrict__ y,
                                                float* wf, int* wi) {
    int z = blockIdx.z;
    if (z && blockIdx.y > blockIdx.x) return;   // xx/yy symmetric: upper triangle suffices
    const float* A = (z==2)? y : x;
    const float* B = (z==0)? y : ((z==1)? x : y);
    int aqo = (z==2)? U_YSQ : U_XSQ;
    int bqo = (z==1)? U_XSQ : U_YSQ;
    __shared__ float la[128][65];
    __shared__ float lb[128][65];
    __shared__ float laq[128], lbq[128];
    __shared__ float wred[4];
    int tid = threadIdx.x;
    int i0 = blockIdx.y*128, j0 = blockIdx.x*128;
    #pragma unroll
    for (int q=0;q<8;++q){
        int idx = tid + q*256;            // 0..2047 : 128 rows x 16 float4
        int r = idx>>4, c4 = (idx&15)<<2;
        float4 va = *(const float4*)(A + (size_t)(i0+r)*DD + c4);
        la[r][c4]=va.x; la[r][c4+1]=va.y; la[r][c4+2]=va.z; la[r][c4+3]=va.w;
        float4 vb = *(const float4*)(B + (size_t)(j0+r)*DD + c4);
        lb[r][c4]=vb.x; lb[r][c4+1]=vb.y; lb[r][c4+2]=vb.z; lb[r][c4+3]=vb.w;
    }
    if (tid < 128) laq[tid] = wf[aqo + i0 + tid];
    else           lbq[tid-128] = wf[bqo + j0 + (tid-128)];
    __syncthreads();
    int tx = tid & 15, ty = tid >> 4;
    float acc[8][8];
    #pragma unroll
    for (int u=0;u<8;++u)
        #pragma unroll
        for (int s=0;s<8;++s) acc[u][s]=0.f;
    for (int d=0; d<DD; ++d){
        float av[8], bv[8];
        #pragma unroll
        for (int u=0;u<8;++u) av[u]=la[ty+16*u][d];
        #pragma unroll
        for (int s=0;s<8;++s) bv[s]=lb[tx+16*s][d];
        #pragma unroll
        for (int u=0;u<8;++u)
            #pragma unroll
            for (int s=0;s<8;++s) acc[u][s] = fmaf(av[u], bv[s], acc[u][s]);
    }
    float m = 0.f;
    #pragma unroll
    for (int u=0;u<8;++u){
        float aq = laq[ty+16*u];
        #pragma unroll
        for (int s=0;s<8;++s){
            float cst = 0.5f*(aq + lbq[tx+16*s]) - acc[u][s];
            m = fmaxf(m, cst);
        }
    }
    #pragma unroll
    for (int o=32;o;o>>=1) m = fmaxf(m, __shfl_xor(m,o));
    int wid = tid>>6;
    if ((tid&63)==0) wred[wid]=m;
    __syncthreads();
    if (tid==0){
        float mm = fmaxf(fmaxf(wred[0],wred[1]),fmaxf(wred[2],wred[3]));
        atomicMax((unsigned int*)&wi[U_MAXC+z], __float_as_uint(mm));
    }
}

// ---------------- kernel 6: gather compact cost submatrices (+ C^T for xy) ----------------
__global__ __launch_bounds__(256) void k_gather(const float* __restrict__ x,
                                                const float* __restrict__ y,
                                                float* wf, int* wi) {
    __shared__ float xs_[32][65], ys_[32][65];
    __shared__ float cs_[32][33];
    __shared__ float rq[32], cq[32];
    __shared__ int toff_s[NPROB+1];
    int tid = threadIdx.x;
    if (tid <= NPROB) toff_s[tid] = wi[U_TOFF+tid];
    __syncthreads();
    int total = toff_s[NPROB];
    for (int tix = blockIdx.x; tix < total; tix += gridDim.x){
        int p = 0;
        while (toff_s[p+1] <= tix) ++p;
        int nx = wi[U_PNX+p], ny = wi[U_PNY+p];
        int tpr = (ny+31)>>5;
        int loc = tix - toff_s[p];
        int i0 = (loc/tpr)<<5, j0 = (loc%tpr)<<5;
        int rbase = wi[U_PRB+p], cbase = wi[U_PCB+p];
        int rs = wi[U_PRS+p], cs = wi[U_PCS+p];
        const float* rsrc = rs? y : x;
        const float* csrc = cs? y : x;
        const int* rlist = wi + (rs? U_COLS : U_ROWS);
        const int* clist = wi + (cs? U_COLS : U_ROWS);
        int rqo = rs? U_YSQ : U_XSQ;
        int cqo = cs? U_YSQ : U_XSQ;
        size_t coff = (size_t)wi[U_PCOFF+p];
        #pragma unroll
        for (int q=0;q<2;++q){
            int idx4 = tid + q*256;      // 0..511
            int r = idx4>>4, c = (idx4&15)<<2;
            if (i0 + r < nx){
                int gi = rlist[rbase + i0 + r];
                float4 v = *(const float4*)(rsrc + (size_t)gi*DD + c);
                xs_[r][c]=v.x; xs_[r][c+1]=v.y; xs_[r][c+2]=v.z; xs_[r][c+3]=v.w;
                if (c==0) rq[r] = wf[rqo + gi];
            }
            if (j0 + r < ny){
                int gj = clist[cbase + j0 + r];
                float4 v = *(const float4*)(csrc + (size_t)gj*DD + c);
                ys_[r][c]=v.x; ys_[r][c+1]=v.y; ys_[r][c+2]=v.z; ys_[r][c+3]=v.w;
                if (c==0) cq[r] = wf[cqo + gj];
            }
        }
        __syncthreads();
        int r = tid>>3, cb = (tid&7)<<2;
        float cv[4] = {0.f,0.f,0.f,0.f};
        if (i0 + r < nx){
            float acc[4] = {0.f,0.f,0.f,0.f};
            for (int d=0; d<DD; ++d){
                float xv = xs_[r][d];
                #pragma unroll
                for (int q=0;q<4;++q) acc[q] += xv*ys_[cb+q][d];
            }
            float* dst = wf + U_SUBC + coff + (size_t)(i0+r)*ny + j0;
            #pragma unroll
            for (int q=0;q<4;++q){
                int j = cb+q;
                cv[q] = 0.5f*(rq[r]+cq[j]) - acc[q];
                if (j0 + j < ny) dst[j] = cv[q];
            }
        }
        if (p%3 == 0){
            #pragma unroll
            for (int q=0;q<4;++q) cs_[r][cb+q] = cv[q];
            __syncthreads();
            if (j0 + r < ny){
                float* dT = wf + U_SUBC + (size_t)wi[U_PTOF+p] + (size_t)(j0+r)*nx + i0;
                #pragma unroll
                for (int q=0;q<4;++q){
                    int ii = cb+q;
                    if (i0 + ii < nx) dT[ii] = cs_[ii][r];
                }
            }
        }
        __syncthreads();
    }
}

// ---------------- sinkhorn sweep: exact online LSE; 2 rows in flight (r11, measured) -----
#define LD8F(JB, D00,D01,D02,D03,D10,D11,D12,D13, G0,G1,G2,G3) { \
    int ja=(JB)+lane; \
    D00=R0[ja]; D01=R0[ja+64]; D02=R0[ja+128]; D03=R0[ja+192]; \
    D10=R1[ja]; D11=R1[ja+64]; D12=R1[ja+128]; D13=R1[ja+192]; \
    G0=gs[ja];  G1=gs[ja+64];  G2=gs[ja+128];  G3=gs[ja+192]; }

#define PROCF(D0,D1,D2,D3, G0,G1,G2,G3, M, S) { \
    float t0=fmaf(D0,nie2,G0), t1=fmaf(D1,nie2,G1), t2=fmaf(D2,nie2,G2), t3=fmaf(D3,nie2,G3); \
    float cm = fmaxf(fmaxf(t0,t1),fmaxf(t2,t3)); \
    float mn = fmaxf(M, cm); \
    float sm = ex2(t0-mn) + ex2(t1-mn) + ex2(t2-mn) + ex2(t3-mn); \
    S = fmaf(S, ex2(M-mn), sm); \
    M = mn; }

#define LD8C(JB, D00,D01,D02,D03,D10,D11,D12,D13, G0,G1,G2,G3) { \
    int ja=(JB)+lane, jb_=(JB)+lane+64, jc=(JB)+lane+128, jd=(JB)+lane+192; \
    D00 = (ja <ncols)? R0[ja]  : 0.f;  D01 = (jb_<ncols)? R0[jb_] : 0.f; \
    D02 = (jc <ncols)? R0[jc]  : 0.f;  D03 = (jd <ncols)? R0[jd]  : 0.f; \
    D10 = (ja <ncols)? R1[ja]  : 0.f;  D11 = (jb_<ncols)? R1[jb_] : 0.f; \
    D12 = (jc <ncols)? R1[jc]  : 0.f;  D13 = (jd <ncols)? R1[jd]  : 0.f; \
    G0  = (ja <ncols)? gs[ja]  : 0.f;  G1  = (jb_<ncols)? gs[jb_] : 0.f; \
    G2  = (jc <ncols)? gs[jc]  : 0.f;  G3  = (jd <ncols)? gs[jd]  : 0.f; }

#define PROCR(JB, D0,D1,D2,D3, G0,G1,G2,G3, M, S) { \
    int ja=(JB)+lane, jb_=(JB)+lane+64, jc=(JB)+lane+128, jd=(JB)+lane+192; \
    float t0 = (ja <ncols)? fmaf(D0, nie2, G0) : -3e38f; \
    float t1 = (jb_<ncols)? fmaf(D1, nie2, G1) : -3e38f; \
    float t2 = (jc <ncols)? fmaf(D2, nie2, G2) : -3e38f; \
    float t3 = (jd <ncols)? fmaf(D3, nie2, G3) : -3e38f; \
    float cm = fmaxf(fmaxf(t0,t1),fmaxf(t2,t3)); \
    float mn = fmaxf(M, cm); \
    float sm = ex2(t0-mn) + ex2(t1-mn) + ex2(t2-mn) + ex2(t3-mn); \
    S = fmaf(S, ex2(M-mn), sm); \
    M = mn; }

template<bool FIN>
__device__ __forceinline__ void sweep(const float* __restrict__ Cb, int ldc, int nrows, int ncols,
                                      const float* __restrict__ gs, float* __restrict__ pot,
                                      float ie2, float neL, float l2n, int w, int lane,
                                      float* saccSlot)
{
    float nie2 = -ie2;
    float acc = 0.f;
    int nfull = ncols >> 8;
    int rem   = ncols & 255;
    for (int i0 = w*2; i0 < nrows; i0 += 16){        // 8 waves x 2 rows
        int ia = i0;
        bool v1 = (i0+1 < nrows);
        int ib = v1 ? i0+1 : i0;
        const float* R0 = Cb + (size_t)ia*ldc;
        const float* R1 = Cb + (size_t)ib*ldc;
        float m0=-3e38f, m1=-3e38f, S0=0.f, S1=0.f;
        if (nfull){
            float a00,a01,a02,a03,a10,a11,a12,a13, ga0,ga1,ga2,ga3;
            LD8F(0, a00,a01,a02,a03,a10,a11,a12,a13, ga0,ga1,ga2,ga3)
            for (int v=1; v<nfull; ++v){
                float b00,b01,b02,b03,b10,b11,b12,b13, gb0,gb1,gb2,gb3;
                LD8F(v<<8, b00,b01,b02,b03,b10,b11,b12,b13, gb0,gb1,gb2,gb3)
                PROCF(a00,a01,a02,a03, ga0,ga1,ga2,ga3, m0, S0)
                PROCF(a10,a11,a12,a13, ga0,ga1,ga2,ga3, m1, S1)
                a00=b00; a01=b01; a02=b02; a03=b03;
                a10=b10; a11=b11; a12=b12; a13=b13;
                ga0=gb0; ga1=gb1; ga2=gb2; ga3=gb3;
            }
            PROCF(a00,a01,a02,a03, ga0,ga1,ga2,ga3, m0, S0)
            PROCF(a10,a11,a12,a13, ga0,ga1,ga2,ga3, m1, S1)
        }
        if (rem){
            int jb = nfull<<8;
            float c00,c01,c02,c03,c10,c11,c12,c13, gc0,gc1,gc2,gc3;
            LD8C(jb, c00,c01,c02,c03,c10,c11,c12,c13, gc0,gc1,gc2,gc3)
            PROCR(jb, c00,c01,c02,c03, gc0,gc1,gc2,gc3, m0, S0)
            PROCR(jb, c10,c11,c12,c13, gc0,gc1,gc2,gc3, m1, S1)
        }
        // cross-lane exact LSE merge
        #pragma unroll
        for (int o=32;o;o>>=1){
            float mo=__shfl_xor(m0,o), So=__shfl_xor(S0,o);
            float mn=fmaxf(m0,mo); S0=fmaf(S0,ex2(m0-mn),So*ex2(mo-mn)); m0=mn;
            mo=__shfl_xor(m1,o); So=__shfl_xor(S1,o);
            mn=fmaxf(m1,mo); S1=fmaf(S1,ex2(m1-mn),So*ex2(mo-mn)); m1=mn;
        }
        if (lane==0){
            float v0  = neL*(m0 + lg2(S0) - l2n);
            float v1v = neL*(m1 + lg2(S1) - l2n);
            if (FIN){
                acc += v0;
                if (v1) acc += v1v;
            } else {
                sst(&pot[ia], v0);
                if (v1) sst(&pot[ib], v1v);
            }
        }
    }
    if (FIN && lane==0 && acc != 0.f) atomicAdd(saccSlot, acc);
}

// ---------------- per-team barrier: RELAXED atomics only (proven r10/r11/r12) -----------
__device__ __forceinline__ void tbar(int* cnt, int* gen, int tpp){
    __syncthreads();
    if (threadIdx.x == 0){
        asm volatile("s_waitcnt vmcnt(0)" ::: "memory");
        int g0 = __hip_atomic_load(gen, __ATOMIC_RELAXED, __HIP_MEMORY_SCOPE_AGENT);
        int a  = __hip_atomic_fetch_add(cnt, 1, __ATOMIC_RELAXED, __HIP_MEMORY_SCOPE_AGENT);
        if (a == tpp-1){
            __hip_atomic_store(cnt, 0, __ATOMIC_RELAXED, __HIP_MEMORY_SCOPE_AGENT);
            __hip_atomic_fetch_add(gen, 1, __ATOMIC_RELAXED, __HIP_MEMORY_SCOPE_AGENT);
        } else {
            int spins = 0;
            while (__hip_atomic_load(gen, __ATOMIC_RELAXED, __HIP_MEMORY_SCOPE_AGENT) == g0){
                __builtin_amdgcn_s_sleep(2);
                if (++spins > 200000) break;   // failsafe: finite wrong run, never a hang
            }
        }
    }
    __syncthreads();
}

// ---------------- kernel 7: persistent sinkhorn — r11 structure (measured 390us) --------
__global__ __launch_bounds__(512) void k_sink(float* wf, int* wi, float* out) {
    int av = wi[U_ASGN + blockIdx.x];
    int p  = av>>16, sb = av & 0xFFFF;
    if (p >= NPROB) return;
    int nx = wi[U_PNX+p], ny = wi[U_PNY+p];
    if (nx <= 0 || ny <= 0) return;
    int tpp = wi[U_TPPA+p];
    int tid = threadIdx.x, w = tid>>6, lane = tid&63;
    float eps0 = fmaxf(__uint_as_float((unsigned)wi[U_MAXC + (p%3)]), C_EPS);
    const float* C  = wf + U_SUBC + (size_t)wi[U_PCOFF+p];
    const float* CT = wf + U_SUBC + (size_t)wi[U_PTOF+p];
    float* f = wf + U_FPOT + p*3072;
    float* g = wf + U_GPOT + p*3072;
    float l2ny = lg2((float)ny), l2nx = lg2((float)nx);
    int* cnt = wi + U_BAR + p*64;
    int* gen = cnt + 32;
    int rb0 = (sb*nx)/tpp, re0 = ((sb+1)*nx)/tpp;   // this block's f-rows
    int cb0 = (sb*ny)/tpp, ce0 = ((sb+1)*ny)/tpp;   // this block's g-rows (CT rows)
    __shared__ float gs[3072];

    for (int it=0; it<C_NITER; ++it){
        float eps = fmaxf(eps0*ex2((float)it*L2_SCAL2), C_EPS);
        float ie2 = LOG2E/eps, neL = -eps*LN2F;
        for (int j=tid; j<ny; j+=512) gs[j] = sld(g+j)*ie2;
        __syncthreads();
        sweep<false>(C + (size_t)rb0*ny, ny, re0-rb0, ny, gs, f+rb0, ie2, neL, l2ny, w, lane, nullptr);
        tbar(cnt, gen, tpp);
        for (int i=tid; i<nx; i+=512) gs[i] = sld(f+i)*ie2;
        __syncthreads();
        sweep<false>(CT + (size_t)cb0*nx, nx, ce0-cb0, nx, gs, g+cb0, ie2, neL, l2nx, w, lane, nullptr);
        tbar(cnt, gen, tpp);
    }
    {
        float ie2 = LOG2E/C_EPS, neL = -C_EPS*LN2F;
        for (int j=tid; j<ny; j+=512) gs[j] = sld(g+j)*ie2;
        __syncthreads();
        sweep<true>(C + (size_t)rb0*ny, ny, re0-rb0, ny, gs, nullptr, ie2, neL, l2ny, w, lane, &wf[U_ACCF+p]);
        __syncthreads();
        for (int i=tid; i<nx; i+=512) gs[i] = sld(f+i)*ie2;
        __syncthreads();
        sweep<true>(CT + (size_t)cb0*nx, nx, ce0-cb0, nx, gs, nullptr, ie2, neL, l2nx, w, lane, &wf[U_ACCG+p]);
    }
}

// ---------------- kernel 8: finalize ----------------
__global__ void k_final(float* wf, int* wi, float* out) {
    if (threadIdx.x != 0 || blockIdx.x != 0) return;
    float s = 0.f;
    for (int p=0; p<NPROB; ++p){
        int nx = wi[U_PNX+p], ny = wi[U_PNY+p];
        if (nx<=0 || ny<=0) continue;
        float wgt = (p%3==0) ? 1.f : -0.5f;
        s += wgt * (wf[U_ACCF+p]/(float)nx + wf[U_ACCG+p]/(float)ny);
    }
    out[0] += s;
}

extern "C" void kernel_launch(void* const* d_in, const int* in_sizes, int n_in,
                              void* d_out, int out_size, void* d_ws, size_t ws_size,
                              hipStream_t stream) {
    const float* x     = (const float*)d_in[0];
    const float* y     = (const float*)d_in[1];
    const float* cc    = (const float*)d_in[2];
    const float* ft    = (const float*)d_in[3];
    const int*   predt = (const int*)d_in[4];
    float* out = (float*)d_out;
    float* wf = (float*)d_ws;
    int*   wi = (int*)d_ws;

    hipMemsetAsync(d_ws, 0, 2432*sizeof(int), stream);                    // counters + barriers (one node)
    hipMemsetAsync(wf + U_GPOT, 0, NPROB*3072*sizeof(float), stream);     // g potentials start at 0

    k_prep<<<24, 256, 0, stream>>>(x, y, cc, predt, wf, wi);
    k_offsets<<<1, 64, 0, stream>>>(ft, wf, wi, out);   // out[0]=loss_fil; tables; team alloc
    k_scatter<<<24, 256, 0, stream>>>(predt, wi);
    k_maxmat<<<dim3(24,24,3), 256, 0, stream>>>(x, y, wf, wi);
    k_gather<<<1024, 256, 0, stream>>>(x, y, wf, wi);

    k_sink<<<NBLK, 512, 0, stream>>>(wf, wi, out);      // persistent, fence-free teams
    k_final<<<1, 64, 0, stream>>>(wf, wi, out);
}

// Round 15
// 597.920 us; speedup vs baseline: 1.3304x; 1.1627x over previous
//
#include <hip/hip_runtime.h>
#include <hip/hip_bf16.h>
#include <float.h>

#define NN 3072
#define MM 3072
#define DD 64
#define KK 8
#define NPROB 24
#define NBLK 480          // persistent k_sink blocks (512 thr each; ~2/CU, balanced)

constexpr float C_EPS   = 0.0025f;   // blur^2
constexpr int   C_NITER = 30;
constexpr float LOG2E = 1.4426950408889634f;
constexpr float LN2F  = 0.6931471805599453f;
constexpr float L2_SCAL2 = -0.6438561897747247f;   // log2(0.64)

__device__ __forceinline__ float ex2(float x){ return __builtin_amdgcn_exp2f(x); }
__device__ __forceinline__ float lg2(float x){ return __builtin_amdgcn_logf(x); }

// system-scope relaxed ops: die-level coherent LLC, NO cache invalidation.
__device__ __forceinline__ void  sst(float* p, float v){
    __hip_atomic_store(p, v, __ATOMIC_RELAXED, __HIP_MEMORY_SCOPE_SYSTEM);
}
__device__ __forceinline__ float sld(const float* p){
    return __hip_atomic_load((float*)p, __ATOMIC_RELAXED, __HIP_MEMORY_SCOPE_SYSTEM);
}

// workspace layout in 4-byte units
#define U_FILL 0        // 8 floats  (zeroed by memset)
#define U_MAXC 8        // 4 uints   (zeroed)
#define U_CNTX 12       // 8 int
#define U_CNTY 20       // 8 int
#define U_POSX 28       // 8 int
#define U_POSY 36       // 8 int
#define U_OFFX 44       // 9 int
#define U_OFFY 53       // 9 int
#define U_PNX  64       // 24 int
#define U_PNY  88
#define U_PRB  112
#define U_PCB  136
#define U_PRS  160
#define U_PCS  184
#define U_PCOFF 208     // 25 int
#define U_PTOF  233     // 24 int  (C^T offsets; == PCOFF for symmetric xx/yy)
#define U_TOFF  257     // 25 int
#define U_ACCF  288     // 24 float (zeroed in k_offsets)
#define U_ACCG  312     // 24 float
#define U_TPPA  336     // 24 int team sizes
#define U_ASGN  384     // NBLK ints: (p<<16)|sb
#define U_BAR   896     // 24 teams x 64 ints: cnt at p*64, gen at p*64+32 (zeroed)
#define U_XSQ  2432     // 3072 float     <- single memset covers [0, 2432)
#define U_YSQ  5504     // 3072 float
#define U_PRED 8576     // 3072 int
#define U_ROWS 11648    // 3072 int
#define U_COLS 14720    // 3072 int
#define U_FPOT 17792    // 24*3072 float potentials f
#define U_GPOT 91520    // 24*3072 float potentials g (zeroed by memset)
#define U_SUBC 165248   // compact submatrices C, then appended C^T blocks (floats)

// ---------------- kernel 1: merged prep (blocks 0-11: x side, 12-23: y side) -------------
__global__ __launch_bounds__(256) void k_prep(const float* __restrict__ x,
                                              const float* __restrict__ y,
                                              const float* __restrict__ cc,
                                              const int* __restrict__ predt,
                                              float* wf, int* wi) {
    int tid = threadIdx.x;
    if (blockIdx.x < 12) {
        __shared__ __align__(16) float c_s[KK][DD];
        __shared__ float csq_s[KK];
        __shared__ float fpart[KK];
        for (int e = tid; e < KK*DD; e += 256) c_s[e>>6][e&63] = cc[e];
        if (tid < KK) fpart[tid] = 0.f;
        __syncthreads();
        if (tid < KK) { float s=0.f; for (int d=0; d<DD; ++d){ float v=c_s[tid][d]; s+=v*v; } csq_s[tid]=s; }
        __syncthreads();
        int i = blockIdx.x*256 + tid;
        if (i < NN) {
            const float4* xr = (const float4*)(x + (size_t)i*DD);
            float4 xv[16];
            float xs = 0.f;
            #pragma unroll
            for (int q=0;q<16;++q){ xv[q]=xr[q];
                xs += xv[q].x*xv[q].x + xv[q].y*xv[q].y + xv[q].z*xv[q].z + xv[q].w*xv[q].w; }
            float dk[KK];
            #pragma unroll
            for (int k=0;k<KK;++k){
                const float4* cr = (const float4*)(&c_s[k][0]);
                float dot=0.f;
                #pragma unroll
                for (int q=0;q<16;++q){ float4 cv=cr[q];
                    dot += xv[q].x*cv.x + xv[q].y*cv.y + xv[q].z*cv.z + xv[q].w*cv.w; }
                dk[k] = xs + csq_s[k] - 2.f*dot;
            }
            float dmin = dk[0]; int am=0;
            #pragma unroll
            for (int k=1;k<KK;++k){ if (dk[k] < dmin){ dmin=dk[k]; am=k; } }
            float se=0.f; float ek[KK];
            #pragma unroll
            for (int k=0;k<KK;++k){ ek[k] = ex2((dmin-dk[k])*LOG2E); se+=ek[k]; }
            float inv = 1.f/se;
            #pragma unroll
            for (int k=0;k<KK;++k) atomicAdd(&fpart[k], ek[k]*inv);
            wf[U_XSQ + i] = xs;
            wi[U_PRED + i] = am;
            atomicAdd(&wi[U_CNTX + am], 1);
        }
        __syncthreads();
        if (tid < KK) atomicAdd(&wf[U_FILL + tid], fpart[tid]);
    } else {
        int j = (blockIdx.x-12)*256 + tid;
        if (j < MM) {
            const float4* yr = (const float4*)(y + (size_t)j*DD);
            float s=0.f;
            #pragma unroll
            for (int q=0;q<16;++q){ float4 v=yr[q]; s += v.x*v.x+v.y*v.y+v.z*v.z+v.w*v.w; }
            wf[U_YSQ + j] = s;
            atomicAdd(&wi[U_CNTY + predt[j]], 1);
        }
    }
}

// ---------------- kernel 3: tables + team allocation (LDS arrays, parallel ASGN) ---------
__global__ __launch_bounds__(512) void k_offsets(const float* __restrict__ ftarg,
                                                 float* wf, int* wi, float* out) {
    __shared__ int wk_s[NPROB];
    __shared__ int q_s[NPROB];
    __shared__ int cq_s[NPROB+1];
    int tid = threadIdx.x;
    if (tid == 0){
        int offx=0, offy=0;
        wi[U_OFFX]=0; wi[U_OFFY]=0;
        for (int k=0;k<KK;++k){
            offx += wi[U_CNTX+k]; wi[U_OFFX+k+1]=offx;
            offy += wi[U_CNTY+k]; wi[U_OFFY+k+1]=offy;
        }
        int co=0, to=0;
        for (int k=0;k<KK;++k){
            int cx=wi[U_CNTX+k], cy=wi[U_CNTY+k];
            bool val = (cx>0)&&(cy>0);
            for (int t=0;t<3;++t){
                int p=k*3+t;
                int nx = val ? (t==2?cy:cx) : 0;
                int ny = val ? (t==1?cx:cy) : 0;
                wi[U_PNX+p]=nx; wi[U_PNY+p]=ny;
                wi[U_PRB+p] = (t==2)? wi[U_OFFY+k] : wi[U_OFFX+k];
                wi[U_PCB+p] = (t==1)? wi[U_OFFX+k] : wi[U_OFFY+k];
                wi[U_PRS+p] = (t==2)?1:0;
                wi[U_PCS+p] = (t==1)?0:1;
                wi[U_PCOFF+p]=co; co += nx*ny;
                wi[U_TOFF+p]=to; to += ((nx+31)>>5)*((ny+31)>>5);
                wf[U_ACCF+p]=0.f; wf[U_ACCG+p]=0.f;
                wk_s[p] = val ? nx*ny : 0;
            }
        }
        wi[U_PCOFF+NPROB]=co; wi[U_TOFF+NPROB]=to;
        // C^T blocks appended after all C; xx/yy are symmetric so CT == C
        int cto = co;
        for (int p=0;p<NPROB;++p){
            if (p%3 == 0){ wi[U_PTOF+p] = cto; cto += wi[U_PNX+p]*wi[U_PNY+p]; }
            else         { wi[U_PTOF+p] = wi[U_PCOFF+p]; }
        }
        // ---- work-proportional quotas (same logic as r14, arrays in LDS) ----
        long long wsum = 0;
        for (int p=0;p<NPROB;++p) wsum += wk_s[p];
        if (wsum == 0){
            for (int p=0;p<NPROB;++p){ q_s[p]=0; wi[U_TPPA+p]=0; }
        } else {
            int tot=0;
            for (int p=0;p<NPROB;++p){
                int q = (wk_s[p]>0) ? (int)(((long long)NBLK*wk_s[p])/wsum) : 0;
                if (wk_s[p]>0 && q<1) q=1;
                q_s[p]=q; tot += q;
            }
            while (tot < NBLK){
                int best=-1; float br=-1.f;
                for (int p=0;p<NPROB;++p) if (wk_s[p]>0){
                    float r = (float)wk_s[p]/(float)q_s[p];
                    if (r>br){br=r;best=p;}
                }
                q_s[best]++; tot++;
            }
            while (tot > NBLK){
                int best=-1; float br=3.4e38f;
                for (int p=0;p<NPROB;++p) if (q_s[p]>1){
                    float r = (float)wk_s[p]/(float)(q_s[p]-1);
                    if (r<br){br=r;best=p;}
                }
                if (best<0) break;
                q_s[best]--; tot--;
            }
            for (int p=0;p<NPROB;++p) wi[U_TPPA+p]=q_s[p];
        }
        // prefix sums of quotas
        int acc2=0;
        for (int p=0;p<NPROB;++p){ cq_s[p]=acc2; acc2 += (wsum==0)?0:q_s[p]; }
        cq_s[NPROB]=acc2;
        float lf=0.f;
        for (int k=0;k<KK;++k){ float fx = wf[U_FILL+k]/(float)NN; float dd = fx - ftarg[k]; lf += dd*dd; }
        out[0] = lf/(float)KK;
    }
    __syncthreads();
    // ---- parallel block->(p,sb) assignment via quota prefix (contiguous teams) ----
    for (int b = tid; b < NBLK; b += 512){
        int p = 0;
        while (p < NPROB && cq_s[p+1] <= b) ++p;
        int v = (p >= NPROB || b >= cq_s[NPROB]) ? (0xFF<<16) : ((p<<16) | (b - cq_s[p]));
        wi[U_ASGN + b] = v;
    }
}

// ---------------- kernel 4: scatter compact index lists ----------------
__global__ __launch_bounds__(256) void k_scatter(const int* __restrict__ predt, int* wi) {
    int b = blockIdx.x;
    if (b < 12) {
        int i = b*256 + threadIdx.x;
        if (i < NN){ int k = wi[U_PRED+i]; int p = atomicAdd(&wi[U_POSX+k],1);
                     wi[U_ROWS + wi[U_OFFX+k] + p] = i; }
    } else {
        int j = (b-12)*256 + threadIdx.x;
        if (j < MM){ int k = predt[j]; int p = atomicAdd(&wi[U_POSY+k],1);
                     wi[U_COLS + wi[U_OFFY+k] + p] = j; }
    }
}

// ---------------- kernel 5: exact max, 128x128 tiles, 8x8/thread strided, tri-skip -------
__global__ __launch_bounds__(256) void k_maxmat(const float* __restrict__ x,
                                                const float* __restrict__ y,
                                                float* wf, int* wi) {
    int z = blockIdx.z;
    if (z && blockIdx.y > blockIdx.x) return;   // xx/yy symmetric: upper triangle suffices
    const float* A = (z==2)? y : x;
    const float* B = (z==0)? y : ((z==1)? x : y);
    int aqo = (z==2)? U_YSQ : U_XSQ;
    int bqo = (z==1)? U_XSQ : U_YSQ;
    __shared__ float la[128][65];
    __shared__ float lb[128][65];
    __shared__ float laq[128], lbq[128];
    __shared__ float wred[4];
    int tid = threadIdx.x;
    int i0 = blockIdx.y*128, j0 = blockIdx.x*128;
    #pragma unroll
    for (int q=0;q<8;++q){
        int idx = tid + q*256;            // 0..2047 : 128 rows x 16 float4
        int r = idx>>4, c4 = (idx&15)<<2;
        float4 va = *(const float4*)(A + (size_t)(i0+r)*DD + c4);
        la[r][c4]=va.x; la[r][c4+1]=va.y; la[r][c4+2]=va.z; la[r][c4+3]=va.w;
        float4 vb = *(const float4*)(B + (size_t)(j0+r)*DD + c4);
        lb[r][c4]=vb.x; lb[r][c4+1]=vb.y; lb[r][c4+2]=vb.z; lb[r][c4+3]=vb.w;
    }
    if (tid < 128) laq[tid] = wf[aqo + i0 + tid];
    else           lbq[tid-128] = wf[bqo + j0 + (tid-128)];
    __syncthreads();
    int tx = tid & 15, ty = tid >> 4;
    float acc[8][8];
    #pragma unroll
    for (int u=0;u<8;++u)
        #pragma unroll
        for (int s=0;s<8;++s) acc[u][s]=0.f;
    for (int d=0; d<DD; ++d){
        float av[8], bv[8];
        #pragma unroll
        for (int u=0;u<8;++u) av[u]=la[ty+16*u][d];
        #pragma unroll
        for (int s=0;s<8;++s) bv[s]=lb[tx+16*s][d];
        #pragma unroll
        for (int u=0;u<8;++u)
            #pragma unroll
            for (int s=0;s<8;++s) acc[u][s] = fmaf(av[u], bv[s], acc[u][s]);
    }
    float m = 0.f;
    #pragma unroll
    for (int u=0;u<8;++u){
        float aq = laq[ty+16*u];
        #pragma unroll
        for (int s=0;s<8;++s){
            float cst = 0.5f*(aq + lbq[tx+16*s]) - acc[u][s];
            m = fmaxf(m, cst);
        }
    }
    #pragma unroll
    for (int o=32;o;o>>=1) m = fmaxf(m, __shfl_xor(m,o));
    int wid = tid>>6;
    if ((tid&63)==0) wred[wid]=m;
    __syncthreads();
    if (tid==0){
        float mm = fmaxf(fmaxf(wred[0],wred[1]),fmaxf(wred[2],wred[3]));
        atomicMax((unsigned int*)&wi[U_MAXC+z], __float_as_uint(mm));
    }
}

// ---------------- kernel 6: gather compact cost submatrices (+ C^T for xy) ----------------
__global__ __launch_bounds__(256) void k_gather(const float* __restrict__ x,
                                                const float* __restrict__ y,
                                                float* wf, int* wi) {
    __shared__ float xs_[32][65], ys_[32][65];
    __shared__ float cs_[32][33];
    __shared__ float rq[32], cq[32];
    __shared__ int toff_s[NPROB+1];
    int tid = threadIdx.x;
    if (tid <= NPROB) toff_s[tid] = wi[U_TOFF+tid];
    __syncthreads();
    int total = toff_s[NPROB];
    for (int tix = blockIdx.x; tix < total; tix += gridDim.x){
        int p = 0;
        while (toff_s[p+1] <= tix) ++p;
        int nx = wi[U_PNX+p], ny = wi[U_PNY+p];
        int tpr = (ny+31)>>5;
        int loc = tix - toff_s[p];
        int i0 = (loc/tpr)<<5, j0 = (loc%tpr)<<5;
        int rbase = wi[U_PRB+p], cbase = wi[U_PCB+p];
        int rs = wi[U_PRS+p], cs = wi[U_PCS+p];
        const float* rsrc = rs? y : x;
        const float* csrc = cs? y : x;
        const int* rlist = wi + (rs? U_COLS : U_ROWS);
        const int* clist = wi + (cs? U_COLS : U_ROWS);
        int rqo = rs? U_YSQ : U_XSQ;
        int cqo = cs? U_YSQ : U_XSQ;
        size_t coff = (size_t)wi[U_PCOFF+p];
        #pragma unroll
        for (int q=0;q<2;++q){
            int idx4 = tid + q*256;      // 0..511
            int r = idx4>>4, c = (idx4&15)<<2;
            if (i0 + r < nx){
                int gi = rlist[rbase + i0 + r];
                float4 v = *(const float4*)(rsrc + (size_t)gi*DD + c);
                xs_[r][c]=v.x; xs_[r][c+1]=v.y; xs_[r][c+2]=v.z; xs_[r][c+3]=v.w;
                if (c==0) rq[r] = wf[rqo + gi];
            }
            if (j0 + r < ny){
                int gj = clist[cbase + j0 + r];
                float4 v = *(const float4*)(csrc + (size_t)gj*DD + c);
                ys_[r][c]=v.x; ys_[r][c+1]=v.y; ys_[r][c+2]=v.z; ys_[r][c+3]=v.w;
                if (c==0) cq[r] = wf[cqo + gj];
            }
        }
        __syncthreads();
        int r = tid>>3, cb = (tid&7)<<2;
        float cv[4] = {0.f,0.f,0.f,0.f};
        if (i0 + r < nx){
            float acc[4] = {0.f,0.f,0.f,0.f};
            for (int d=0; d<DD; ++d){
                float xv = xs_[r][d];
                #pragma unroll
                for (int q=0;q<4;++q) acc[q] += xv*ys_[cb+q][d];
            }
            float* dst = wf + U_SUBC + coff + (size_t)(i0+r)*ny + j0;
            #pragma unroll
            for (int q=0;q<4;++q){
                int j = cb+q;
                cv[q] = 0.5f*(rq[r]+cq[j]) - acc[q];
                if (j0 + j < ny) dst[j] = cv[q];
            }
        }
        if (p%3 == 0){
            #pragma unroll
            for (int q=0;q<4;++q) cs_[r][cb+q] = cv[q];
            __syncthreads();
            if (j0 + r < ny){
                float* dT = wf + U_SUBC + (size_t)wi[U_PTOF+p] + (size_t)(j0+r)*nx + i0;
                #pragma unroll
                for (int q=0;q<4;++q){
                    int ii = cb+q;
                    if (i0 + ii < nx) dT[ii] = cs_[ii][r];
                }
            }
        }
        __syncthreads();
    }
}

// ---------------- sinkhorn sweep: exact online LSE; 2 rows in flight (r11, measured) -----
#define LD8F(JB, D00,D01,D02,D03,D10,D11,D12,D13, G0,G1,G2,G3) { \
    int ja=(JB)+lane; \
    D00=R0[ja]; D01=R0[ja+64]; D02=R0[ja+128]; D03=R0[ja+192]; \
    D10=R1[ja]; D11=R1[ja+64]; D12=R1[ja+128]; D13=R1[ja+192]; \
    G0=gs[ja];  G1=gs[ja+64];  G2=gs[ja+128];  G3=gs[ja+192]; }

#define PROCF(D0,D1,D2,D3, G0,G1,G2,G3, M, S) { \
    float t0=fmaf(D0,nie2,G0), t1=fmaf(D1,nie2,G1), t2=fmaf(D2,nie2,G2), t3=fmaf(D3,nie2,G3); \
    float cm = fmaxf(fmaxf(t0,t1),fmaxf(t2,t3)); \
    float mn = fmaxf(M, cm); \
    float sm = ex2(t0-mn) + ex2(t1-mn) + ex2(t2-mn) + ex2(t3-mn); \
    S = fmaf(S, ex2(M-mn), sm); \
    M = mn; }

#define LD8C(JB, D00,D01,D02,D03,D10,D11,D12,D13, G0,G1,G2,G3) { \
    int ja=(JB)+lane, jb_=(JB)+lane+64, jc=(JB)+lane+128, jd=(JB)+lane+192; \
    D00 = (ja <ncols)? R0[ja]  : 0.f;  D01 = (jb_<ncols)? R0[jb_] : 0.f; \
    D02 = (jc <ncols)? R0[jc]  : 0.f;  D03 = (jd <ncols)? R0[jd]  : 0.f; \
    D10 = (ja <ncols)? R1[ja]  : 0.f;  D11 = (jb_<ncols)? R1[jb_] : 0.f; \
    D12 = (jc <ncols)? R1[jc]  : 0.f;  D13 = (jd <ncols)? R1[jd]  : 0.f; \
    G0  = (ja <ncols)? gs[ja]  : 0.f;  G1  = (jb_<ncols)? gs[jb_] : 0.f; \
    G2  = (jc <ncols)? gs[jc]  : 0.f;  G3  = (jd <ncols)? gs[jd]  : 0.f; }

#define PROCR(JB, D0,D1,D2,D3, G0,G1,G2,G3, M, S) { \
    int ja=(JB)+lane, jb_=(JB)+lane+64, jc=(JB)+lane+128, jd=(JB)+lane+192; \
    float t0 = (ja <ncols)? fmaf(D0, nie2, G0) : -3e38f; \
    float t1 = (jb_<ncols)? fmaf(D1, nie2, G1) : -3e38f; \
    float t2 = (jc <ncols)? fmaf(D2, nie2, G2) : -3e38f; \
    float t3 = (jd <ncols)? fmaf(D3, nie2, G3) : -3e38f; \
    float cm = fmaxf(fmaxf(t0,t1),fmaxf(t2,t3)); \
    float mn = fmaxf(M, cm); \
    float sm = ex2(t0-mn) + ex2(t1-mn) + ex2(t2-mn) + ex2(t3-mn); \
    S = fmaf(S, ex2(M-mn), sm); \
    M = mn; }

template<bool FIN>
__device__ __forceinline__ void sweep(const float* __restrict__ Cb, int ldc, int nrows, int ncols,
                                      const float* __restrict__ gs, float* __restrict__ pot,
                                      float ie2, float neL, float l2n, int w, int lane,
                                      float* saccSlot)
{
    float nie2 = -ie2;
    float acc = 0.f;
    int nfull = ncols >> 8;
    int rem   = ncols & 255;
    for (int i0 = w*2; i0 < nrows; i0 += 16){        // 8 waves x 2 rows
        int ia = i0;
        bool v1 = (i0+1 < nrows);
        int ib = v1 ? i0+1 : i0;
        const float* R0 = Cb + (size_t)ia*ldc;
        const float* R1 = Cb + (size_t)ib*ldc;
        float m0=-3e38f, m1=-3e38f, S0=0.f, S1=0.f;
        if (nfull){
            float a00,a01,a02,a03,a10,a11,a12,a13, ga0,ga1,ga2,ga3;
            LD8F(0, a00,a01,a02,a03,a10,a11,a12,a13, ga0,ga1,ga2,ga3)
            for (int v=1; v<nfull; ++v){
                float b00,b01,b02,b03,b10,b11,b12,b13, gb0,gb1,gb2,gb3;
                LD8F(v<<8, b00,b01,b02,b03,b10,b11,b12,b13, gb0,gb1,gb2,gb3)
                PROCF(a00,a01,a02,a03, ga0,ga1,ga2,ga3, m0, S0)
                PROCF(a10,a11,a12,a13, ga0,ga1,ga2,ga3, m1, S1)
                a00=b00; a01=b01; a02=b02; a03=b03;
                a10=b10; a11=b11; a12=b12; a13=b13;
                ga0=gb0; ga1=gb1; ga2=gb2; ga3=gb3;
            }
            PROCF(a00,a01,a02,a03, ga0,ga1,ga2,ga3, m0, S0)
            PROCF(a10,a11,a12,a13, ga0,ga1,ga2,ga3, m1, S1)
        }
        if (rem){
            int jb = nfull<<8;
            float c00,c01,c02,c03,c10,c11,c12,c13, gc0,gc1,gc2,gc3;
            LD8C(jb, c00,c01,c02,c03,c10,c11,c12,c13, gc0,gc1,gc2,gc3)
            PROCR(jb, c00,c01,c02,c03, gc0,gc1,gc2,gc3, m0, S0)
            PROCR(jb, c10,c11,c12,c13, gc0,gc1,gc2,gc3, m1, S1)
        }
        // cross-lane exact LSE merge
        #pragma unroll
        for (int o=32;o;o>>=1){
            float mo=__shfl_xor(m0,o), So=__shfl_xor(S0,o);
            float mn=fmaxf(m0,mo); S0=fmaf(S0,ex2(m0-mn),So*ex2(mo-mn)); m0=mn;
            mo=__shfl_xor(m1,o); So=__shfl_xor(S1,o);
            mn=fmaxf(m1,mo); S1=fmaf(S1,ex2(m1-mn),So*ex2(mo-mn)); m1=mn;
        }
        if (lane==0){
            float v0  = neL*(m0 + lg2(S0) - l2n);
            float v1v = neL*(m1 + lg2(S1) - l2n);
            if (FIN){
                acc += v0;
                if (v1) acc += v1v;
            } else {
                sst(&pot[ia], v0);
                if (v1) sst(&pot[ib], v1v);
            }
        }
    }
    if (FIN && lane==0 && acc != 0.f) atomicAdd(saccSlot, acc);
}

// ---------------- per-team barrier: RELAXED atomics only (proven r10/r11/r12/r14) -------
__device__ __forceinline__ void tbar(int* cnt, int* gen, int tpp){
    __syncthreads();
    if (threadIdx.x == 0){
        asm volatile("s_waitcnt vmcnt(0)" ::: "memory");
        int g0 = __hip_atomic_load(gen, __ATOMIC_RELAXED, __HIP_MEMORY_SCOPE_AGENT);
        int a  = __hip_atomic_fetch_add(cnt, 1, __ATOMIC_RELAXED, __HIP_MEMORY_SCOPE_AGENT);
        if (a == tpp-1){
            __hip_atomic_store(cnt, 0, __ATOMIC_RELAXED, __HIP_MEMORY_SCOPE_AGENT);
            __hip_atomic_fetch_add(gen, 1, __ATOMIC_RELAXED, __HIP_MEMORY_SCOPE_AGENT);
        } else {
            int spins = 0;
            while (__hip_atomic_load(gen, __ATOMIC_RELAXED, __HIP_MEMORY_SCOPE_AGENT) == g0){
                __builtin_amdgcn_s_sleep(2);
                if (++spins > 200000) break;   // failsafe: finite wrong run, never a hang
            }
        }
    }
    __syncthreads();
}

// ---------------- kernel 7: persistent sinkhorn — r11 structure (measured 380us) --------
__global__ __launch_bounds__(512) void k_sink(float* wf, int* wi, float* out) {
    int av = wi[U_ASGN + blockIdx.x];
    int p  = av>>16, sb = av & 0xFFFF;
    if (p >= NPROB) return;
    int nx = wi[U_PNX+p], ny = wi[U_PNY+p];
    if (nx <= 0 || ny <= 0) return;
    int tpp = wi[U_TPPA+p];
    int tid = threadIdx.x, w = tid>>6, lane = tid&63;
    float eps0 = fmaxf(__uint_as_float((unsigned)wi[U_MAXC + (p%3)]), C_EPS);
    const float* C  = wf + U_SUBC + (size_t)wi[U_PCOFF+p];
    const float* CT = wf + U_SUBC + (size_t)wi[U_PTOF+p];
    float* f = wf + U_FPOT + p*3072;
    float* g = wf + U_GPOT + p*3072;
    float l2ny = lg2((float)ny), l2nx = lg2((float)nx);
    int* cnt = wi + U_BAR + p*64;
    int* gen = cnt + 32;
    int rb0 = (sb*nx)/tpp, re0 = ((sb+1)*nx)/tpp;   // this block's f-rows
    int cb0 = (sb*ny)/tpp, ce0 = ((sb+1)*ny)/tpp;   // this block's g-rows (CT rows)
    __shared__ float gs[3072];

    for (int it=0; it<C_NITER; ++it){
        float eps = fmaxf(eps0*ex2((float)it*L2_SCAL2), C_EPS);
        float ie2 = LOG2E/eps, neL = -eps*LN2F;
        for (int j=tid; j<ny; j+=512) gs[j] = sld(g+j)*ie2;
        __syncthreads();
        sweep<false>(C + (size_t)rb0*ny, ny, re0-rb0, ny, gs, f+rb0, ie2, neL, l2ny, w, lane, nullptr);
        tbar(cnt, gen, tpp);
        for (int i=tid; i<nx; i+=512) gs[i] = sld(f+i)*ie2;
        __syncthreads();
        sweep<false>(CT + (size_t)cb0*nx, nx, ce0-cb0, nx, gs, g+cb0, ie2, neL, l2nx, w, lane, nullptr);
        tbar(cnt, gen, tpp);
    }
    {
        float ie2 = LOG2E/C_EPS, neL = -C_EPS*LN2F;
        for (int j=tid; j<ny; j+=512) gs[j] = sld(g+j)*ie2;
        __syncthreads();
        sweep<true>(C + (size_t)rb0*ny, ny, re0-rb0, ny, gs, nullptr, ie2, neL, l2ny, w, lane, &wf[U_ACCF+p]);
        __syncthreads();
        for (int i=tid; i<nx; i+=512) gs[i] = sld(f+i)*ie2;
        __syncthreads();
        sweep<true>(CT + (size_t)cb0*nx, nx, ce0-cb0, nx, gs, nullptr, ie2, neL, l2nx, w, lane, &wf[U_ACCG+p]);
    }
}

// ---------------- kernel 8: finalize ----------------
__global__ void k_final(float* wf, int* wi, float* out) {
    if (threadIdx.x != 0 || blockIdx.x != 0) return;
    float s = 0.f;
    for (int p=0; p<NPROB; ++p){
        int nx = wi[U_PNX+p], ny = wi[U_PNY+p];
        if (nx<=0 || ny<=0) continue;
        float wgt = (p%3==0) ? 1.f : -0.5f;
        s += wgt * (wf[U_ACCF+p]/(float)nx + wf[U_ACCG+p]/(float)ny);
    }
    out[0] += s;
}

extern "C" void kernel_launch(void* const* d_in, const int* in_sizes, int n_in,
                              void* d_out, int out_size, void* d_ws, size_t ws_size,
                              hipStream_t stream) {
    const float* x     = (const float*)d_in[0];
    const float* y     = (const float*)d_in[1];
    const float* cc    = (const float*)d_in[2];
    const float* ft    = (const float*)d_in[3];
    const int*   predt = (const int*)d_in[4];
    float* out = (float*)d_out;
    float* wf = (float*)d_ws;
    int*   wi = (int*)d_ws;

    hipMemsetAsync(d_ws, 0, 2432*sizeof(int), stream);                    // counters + barriers (one node)
    hipMemsetAsync(wf + U_GPOT, 0, NPROB*3072*sizeof(float), stream);     // g potentials start at 0

    k_prep<<<24, 256, 0, stream>>>(x, y, cc, predt, wf, wi);
    k_offsets<<<1, 512, 0, stream>>>(ft, wf, wi, out);  // tables + parallel team assignment
    k_scatter<<<24, 256, 0, stream>>>(predt, wi);
    k_maxmat<<<dim3(24,24,3), 256, 0, stream>>>(x, y, wf, wi);
    k_gather<<<1024, 256, 0, stream>>>(x, y, wf, wi);

    k_sink<<<NBLK, 512, 0, stream>>>(wf, wi, out);      // persistent, fence-free teams
    k_final<<<1, 64, 0, stream>>>(wf, wi, out);
}